// Round 5
// baseline (283.309 us; speedup 1.0000x reference)
//
#include <hip/hip_runtime.h>

#define N 8192
#define D 512
#define NOFF 496                    // off-diagonal 256x256 bricks: 32*31/2
#define NDIAG 32                    // diagonal 256x256 bricks
#define NBRICKS (NOFF + NDIAG)      // 528 = 8 * 66 (clean XCD chunking)
#define MARGIN 0.3f

typedef __attribute__((ext_vector_type(4))) int int4v;
typedef __attribute__((ext_vector_type(8))) int int8v;      // 32 fp8 = 8 VGPRs
typedef __attribute__((ext_vector_type(4))) float f32x4;    // MFMA accumulator

// async global->LDS, 16B per lane; LDS dest = wave-uniform base + lane*16.
__device__ __forceinline__ void gload_lds16(const void* g, void* l) {
    __builtin_amdgcn_global_load_lds(
        (const __attribute__((address_space(1))) void*)g,
        (__attribute__((address_space(3))) void*)l,
        16, 0, 0);
}

// Load one 16x16x128 f8f6f4 operand fragment (32 fp8 = 32 B) for (row, quad)
// from a 128 B/row LDS tile with 16B-chunk XOR swizzle (phys = logi ^ (row&7)).
__device__ __forceinline__ int8v load_frag8(const unsigned char* base, int row, int q) {
    const int v = (2 * q) ^ (row & 7);
    int4v lo = *(const int4v*)(base + row * 128 + v * 16);
    int4v hi = *(const int4v*)(base + row * 128 + (v ^ 1) * 16);
    return __builtin_shufflevector(lo, hi, 0, 1, 2, 3, 4, 5, 6, 7);
}

// Stage one BK=128 K-tile (A 256x128B + B 256x128B fp8) with XOR source-swizzle.
// 512 threads -> 8 gload_lds per thread per tile (4 A + 4 B).
__device__ __forceinline__ void stage_tile(const unsigned char* Ag, unsigned char* Asm,
                                           const unsigned char* Bg, unsigned char* Bsm,
                                           int tid, int k0) {
    #pragma unroll
    for (int s = 0; s < 4; s++) {                           // A: 2048 16B chunks
        int p = s * 512 + tid;
        int r = p >> 3, kc = (p & 7) ^ (r & 7);
        gload_lds16(Ag + (size_t)r * D + k0 + kc * 16, Asm + p * 16);
    }
    #pragma unroll
    for (int s = 0; s < 4; s++) {                           // B: 2048 16B chunks
        int p = s * 512 + tid;
        int r = p >> 3, kc = (p & 7) ^ (r & 7);
        gload_lds16(Bg + (size_t)r * D + k0 + kc * 16, Bsm + p * 16);
    }
}

// Kernel 1: per-row fp32 sum-of-squares (exact) + fp8(e4m3) cast + init.
__global__ void prep_kernel(const float* __restrict__ x,
                            unsigned char* __restrict__ x8,
                            float* __restrict__ sq,
                            unsigned int* __restrict__ apU,
                            unsigned int* __restrict__ anU,
                            int* __restrict__ cnt) {
    if (blockIdx.x == 0 && threadIdx.x == 0) cnt[0] = 0;
    int w = threadIdx.x >> 6, lane = threadIdx.x & 63;
    int row = blockIdx.x * 4 + w;
    const float4* p = (const float4*)(x + (size_t)row * D) + lane * 2;
    float4 v0 = p[0], v1 = p[1];
    float s = v0.x * v0.x + v0.y * v0.y + v0.z * v0.z + v0.w * v0.w
            + v1.x * v1.x + v1.y * v1.y + v1.z * v1.z + v1.w * v1.w;
    int w0 = __builtin_amdgcn_cvt_pk_fp8_f32(v0.x, v0.y, 0, false);
    w0     = __builtin_amdgcn_cvt_pk_fp8_f32(v0.z, v0.w, w0, true);
    int w1 = __builtin_amdgcn_cvt_pk_fp8_f32(v1.x, v1.y, 0, false);
    w1     = __builtin_amdgcn_cvt_pk_fp8_f32(v1.z, v1.w, w1, true);
    ((int2*)(x8 + (size_t)row * D))[lane] = make_int2(w0, w1);
    #pragma unroll
    for (int o = 32; o > 0; o >>= 1) s += __shfl_xor(s, o);
    if (lane == 0) {
        sq[row] = s;
        apU[row] = 0u;                 // max-d^2 accumulator (d^2 clamped >= 0)
        anU[row] = 0x7f800000u;        // min-d^2 accumulator (+inf)
    }
}

// Kernel 2: 256x256 bricks over the upper triangle (32 bands). Blocks
// 0..495 = off-diagonal (ri<cj), 496..527 = diagonal. Bijective XCD swizzle
// (528 = 8x66): consecutive swizzled ids share cj bands within an XCD -> L2
// locality for the B panel.
//
// Rationale: effective staging BW measured ~6.5-7 TB/s across r1/r2/r4
// structures -> time ~ staged bytes. 256^2 bricks halve bytes/pair vs 128^2
// (135 MB total). K-loop is round-2's proven shape scaled: single-buffer
// 64 KB tiles, plain __syncthreads, frags to regs, stage ISSUED right after
// the drain-barrier so the next iteration's drain finds loads ~1 MFMA-cluster
// old. 8 waves, grid 4(wm) x 2(wn): per-wave 64 rows x 128 cols, acc[4][8] =
// 128 AGPR -- identical per-wave profile to round 2. 2 blocks/CU (69.6 KB).
// Gram-matrix property: A and B fragments use the SAME loader, so any
// consistent K-permutation cancels. Diagonal bricks compute both halves
// redundantly (correct; 32/528 bricks).
__global__ __launch_bounds__(512, 4)
void gemm_kernel(const unsigned char* __restrict__ xb,
                 const float* __restrict__ sq,
                 const int* __restrict__ tgt,
                 unsigned int* __restrict__ apU,
                 unsigned int* __restrict__ anU) {
    __shared__ __align__(16) char smem_raw[65536];          // A 32K + B 32K
    __shared__ float sqI[256], sqJ[256];
    __shared__ int tI[256], tJ[256];

    unsigned char* Asm = (unsigned char*)smem_raw;
    unsigned char* Bsm = Asm + 32768;
    // epilogue scratch (aliases tiles; safe after last drain barrier)
    float* rowPap = (float*)smem_raw;                       // [256]
    float* rowPan = rowPap + 256;                           // [256]
    float* colPap = rowPan + 256;                           // [256][5]
    float* colPan = colPap + 256 * 5;                       // [256][5]

    // XCD-chunked bijective swizzle: 528 = 8 XCDs x 66 blocks.
    const int id = (blockIdx.x & 7) * 66 + (blockIdx.x >> 3);
    int ri, cj;
    if (id < NOFF) {
        cj = (int)((1.0f + sqrtf(1.0f + 8.0f * (float)id)) * 0.5f);
        while (cj * (cj - 1) / 2 > id) cj--;
        while ((cj + 1) * cj / 2 <= id) cj++;
        ri = id - cj * (cj - 1) / 2;                        // 0..cj-1
    } else {
        ri = cj = id - NOFF;                                // diagonal
    }
    const int rowBase = ri * 256, colBase = cj * 256;

    const int tid = threadIdx.x;
    const int w = tid >> 6, lane = tid & 63, q = lane >> 4, c = lane & 15;
    const int wm = w & 3, wn = w >> 2;                      // 64-row x 128-col/wave

    if (tid < 256) {
        sqI[tid] = sq[rowBase + tid]; tI[tid] = tgt[rowBase + tid];
        sqJ[tid] = sq[colBase + tid]; tJ[tid] = tgt[colBase + tid];
    }

    const unsigned char* Ag = xb + (size_t)rowBase * D;
    const unsigned char* Bg = xb + (size_t)colBase * D;

    f32x4 acc[4][8] = {};

    stage_tile(Ag, Asm, Bg, Bsm, tid, 0);                   // tile 0

    #pragma unroll
    for (int kk = 0; kk < 4; kk++) {                        // 4 K-iterations
        __syncthreads();                                    // tile kk ready (vmcnt drain)
        int8v af[4], b0[4];
        #pragma unroll
        for (int t = 0; t < 4; t++)
            af[t] = load_frag8(Asm, wm * 64 + t * 16 + c, q);
        #pragma unroll
        for (int t = 0; t < 4; t++)
            b0[t] = load_frag8(Bsm, wn * 128 + t * 16 + c, q);
        // first 16 MFMAs overlap b1's ds_reads
        #pragma unroll
        for (int tm = 0; tm < 4; tm++)
            #pragma unroll
            for (int t = 0; t < 4; t++)
                acc[tm][t] = __builtin_amdgcn_mfma_scale_f32_16x16x128_f8f6f4(
                    af[tm], b0[t], acc[tm][t],
                    0, 0,                                    // FMT A,B = fp8 e4m3
                    0, 0x7F7F7F7Fu, 0, 0x7F7F7F7Fu);         // scales = 1.0
        int8v b1[4];
        #pragma unroll
        for (int t = 0; t < 4; t++)
            b1[t] = load_frag8(Bsm, wn * 128 + (4 + t) * 16 + c, q);
        __syncthreads();                                    // all tile reads drained
        if (kk < 3)                                         // stage EARLY: next drain
            stage_tile(Ag, Asm, Bg, Bsm, tid, (kk + 1) * 128);  // finds loads old
        #pragma unroll
        for (int tm = 0; tm < 4; tm++)                      // 16 MFMAs cover the stage
            #pragma unroll
            for (int t = 0; t < 4; t++)
                acc[tm][4 + t] = __builtin_amdgcn_mfma_scale_f32_16x16x128_f8f6f4(
                    af[tm], b1[t], acc[tm][4 + t],
                    0, 0, 0, 0x7F7F7F7Fu, 0, 0x7F7F7F7Fu);
    }
    // After the last drain barrier no wave reads tiles again -> scratch aliasing
    // below is safe (epilogue readers wait on the epilogue barrier).

    // Epilogue. C/D layout is shape-determined: col=lane&15, row=q*4+reg.
    // d^2-space keys: rk = sq[j]-2p (row side), ck = sq[i]-2p (col side).
    // Row reduce: per-lane over tn, then shfl over c (16-lane group), then
    // cross-wave wn0/wn1 combine via LDS. Col reduce: per-lane over tm/r,
    // shfl over q, then cross-wave wm combine via LDS.
    float sjc[8]; int tjx[8];
    #pragma unroll
    for (int tn = 0; tn < 8; tn++) {
        int col_l = wn * 128 + tn * 16 + c;
        sjc[tn] = sqJ[col_l]; tjx[tn] = tJ[col_l];
    }
    float apc[8], anc[8];
    #pragma unroll
    for (int tn = 0; tn < 8; tn++) { apc[tn] = -1e30f; anc[tn] = 1e30f; }
    float rpk[4][4], rnk[4][4];                             // row partials (kept)
    #pragma unroll
    for (int tm = 0; tm < 4; tm++) {
        #pragma unroll
        for (int r = 0; r < 4; r++) {
            int row_l = wm * 64 + tm * 16 + q * 4 + r;
            float si = sqI[row_l]; int ti = tI[row_l];
            float rp = -1e30f, rn = 1e30f;
            #pragma unroll
            for (int tn = 0; tn < 8; tn++) {
                float p = acc[tm][tn][r];
                bool same = (ti == tjx[tn]);
                float rk = fmaf(-2.0f, p, sjc[tn]);         // row-side key
                float ck = fmaf(-2.0f, p, si);              // col-side key
                rp = fmaxf(rp, same ? rk : -1e30f);
                rn = fminf(rn, same ? 1e30f : rk);
                apc[tn] = fmaxf(apc[tn], same ? ck : -1e30f);
                anc[tn] = fminf(anc[tn], same ? 1e30f : ck);
            }
            #pragma unroll
            for (int o = 1; o < 16; o <<= 1) {              // reduce over c
                rp = fmaxf(rp, __shfl_xor(rp, o));
                rn = fminf(rn, __shfl_xor(rn, o));
            }
            rpk[tm][r] = rp; rnk[tm][r] = rn;
        }
    }
    // wn==1 publishes row partials
    if (wn == 1 && c == 0) {
        #pragma unroll
        for (int tm = 0; tm < 4; tm++)
            #pragma unroll
            for (int r = 0; r < 4; r++) {
                int row_l = wm * 64 + tm * 16 + q * 4 + r;
                rowPap[row_l] = rpk[tm][r];
                rowPan[row_l] = rnk[tm][r];
            }
    }
    // col partials: reduce over q (lanes differing in bits 4-5)
    #pragma unroll
    for (int tn = 0; tn < 8; tn++) {
        apc[tn] = fmaxf(apc[tn], __shfl_xor(apc[tn], 16));
        apc[tn] = fmaxf(apc[tn], __shfl_xor(apc[tn], 32));
        anc[tn] = fminf(anc[tn], __shfl_xor(anc[tn], 16));
        anc[tn] = fminf(anc[tn], __shfl_xor(anc[tn], 32));
    }
    if (q == 0) {                                           // lanes 0..15 publish
        #pragma unroll
        for (int tn = 0; tn < 8; tn++) {
            int col_l = wn * 128 + tn * 16 + c;
            colPap[col_l * 5 + wm] = apc[tn];
            colPan[col_l * 5 + wm] = anc[tn];
        }
    }
    __syncthreads();
    if (wn == 0 && c == 0) {                                // row finalize + atomic
        #pragma unroll
        for (int tm = 0; tm < 4; tm++)
            #pragma unroll
            for (int r = 0; r < 4; r++) {
                int row_l = wm * 64 + tm * 16 + q * 4 + r;
                float ap = fmaxf(rpk[tm][r], rowPap[row_l]);
                float an = fminf(rnk[tm][r], rowPan[row_l]);
                // restore true d^2, clamp >=0: uint-bit cmp == float cmp
                float apd = fmaxf(sqI[row_l] + ap, 0.0f);
                float and_ = fmaxf(sqI[row_l] + an, 0.0f);
                atomicMax(&apU[rowBase + row_l], __float_as_uint(apd));
                atomicMin(&anU[rowBase + row_l], __float_as_uint(and_));
            }
    }
    if (tid < 256) {                                        // col finalize + atomic
        float ap = -1e30f, an = 1e30f;
        #pragma unroll
        for (int u = 0; u < 4; u++) {
            ap = fmaxf(ap, colPap[tid * 5 + u]);
            an = fminf(an, colPan[tid * 5 + u]);
        }
        float apd = fmaxf(sqJ[tid] + ap, 0.0f);
        float and_ = fmaxf(sqJ[tid] + an, 0.0f);
        atomicMax(&apU[colBase + tid], __float_as_uint(apd));  // fire-and-forget
        atomicMin(&anU[colBase + tid], __float_as_uint(and_));
    }
}

// Kernel 3: per-row ap/an final in apU/anU -> sqrt + relu + mean; last block
// (atomic counter) folds the 32 block sums into out[0].
__global__ void reduce_kernel(const unsigned int* __restrict__ apU,
                              const unsigned int* __restrict__ anU,
                              float* __restrict__ bsum, int* __restrict__ cnt,
                              float* __restrict__ out) {
    int tid = threadIdx.x;
    int row = blockIdx.x * 256 + tid;
    float ap = __uint_as_float(apU[row]);
    float an = __uint_as_float(anU[row]);
    float dap = sqrtf(fmaxf(ap, 1e-12f));
    float dan = sqrtf(fmaxf(an, 1e-12f));
    float v = fmaxf(dap - dan + MARGIN, 0.0f);
    #pragma unroll
    for (int o = 32; o > 0; o >>= 1) v += __shfl_xor(v, o);
    __shared__ float ss[4];
    __shared__ int amLast;
    if ((tid & 63) == 0) ss[tid >> 6] = v;
    __syncthreads();
    if (tid == 0) {
        bsum[blockIdx.x] = ss[0] + ss[1] + ss[2] + ss[3];
        __threadfence();
        amLast = (atomicAdd(cnt, 1) == N / 256 - 1);
    }
    __syncthreads();
    if (amLast && tid < 64) {
        __threadfence();
        float t = (tid < N / 256) ? bsum[tid] : 0.0f;
        #pragma unroll
        for (int o = 32; o > 0; o >>= 1) t += __shfl_xor(t, o);
        if (tid == 0) out[0] = t * (1.0f / (float)N);
    }
}

extern "C" void kernel_launch(void* const* d_in, const int* in_sizes, int n_in,
                              void* d_out, int out_size, void* d_ws, size_t ws_size,
                              hipStream_t stream) {
    const float* x  = (const float*)d_in[0];
    const int* tgt  = (const int*)d_in[1];
    float* out      = (float*)d_out;

    char* ws = (char*)d_ws;
    unsigned char* x8 = (unsigned char*)ws;                         // 4 MB fp8 X
    float* sq   = (float*)(ws + (size_t)N * D);                     // 32 KB
    unsigned int* apU = (unsigned int*)(sq + N);                    // 32 KB
    unsigned int* anU = apU + N;                                    // 32 KB
    float* bsum = (float*)(anU + N);                                // 128 B
    int* cnt = (int*)(bsum + 32);

    prep_kernel<<<N / 4, 256, 0, stream>>>(x, x8, sq, apU, anU, cnt);
    gemm_kernel<<<NBRICKS, 512, 0, stream>>>(x8, sq, tgt, apU, anU);
    reduce_kernel<<<N / 256, 256, 0, stream>>>(apU, anU, bsum, cnt, out);
}

// Round 6
// 123.450 us; speedup vs baseline: 2.2949x; 2.2949x over previous
//
#include <hip/hip_runtime.h>

#define N 8192
#define D 512
#define NOFF 496                    // off-diagonal 256x256 bricks: 32*31/2
#define NDIAG 32                    // diagonal 256x256 bricks
#define NBRICKS (NOFF + NDIAG)      // 528 = 8 * 66 (clean XCD chunking)
#define MARGIN 0.3f

typedef __attribute__((ext_vector_type(4))) int int4v;
typedef __attribute__((ext_vector_type(8))) int int8v;      // 32 fp8 = 8 VGPRs
typedef __attribute__((ext_vector_type(4))) float f32x4;    // MFMA accumulator

// async global->LDS, 16B per lane; LDS dest = wave-uniform base + lane*16.
__device__ __forceinline__ void gload_lds16(const void* g, void* l) {
    __builtin_amdgcn_global_load_lds(
        (const __attribute__((address_space(1))) void*)g,
        (__attribute__((address_space(3))) void*)l,
        16, 0, 0);
}

// Load one 16x16x128 f8f6f4 operand fragment (32 fp8 = 32 B) for (row, quad)
// from a 128 B/row LDS tile with 16B-chunk XOR swizzle (phys = logi ^ (row&7)).
__device__ __forceinline__ int8v load_frag8(const unsigned char* base, int row, int q) {
    const int v = (2 * q) ^ (row & 7);
    int4v lo = *(const int4v*)(base + row * 128 + v * 16);
    int4v hi = *(const int4v*)(base + row * 128 + (v ^ 1) * 16);
    return __builtin_shufflevector(lo, hi, 0, 1, 2, 3, 4, 5, 6, 7);
}

// Stage one BK=128 K-tile (A 256x128B + B 256x128B fp8) with XOR source-swizzle.
// 512 threads -> 8 gload_lds per thread per tile (4 A + 4 B).
__device__ __forceinline__ void stage_tile(const unsigned char* Ag, unsigned char* Asm,
                                           const unsigned char* Bg, unsigned char* Bsm,
                                           int tid, int k0) {
    #pragma unroll
    for (int s = 0; s < 4; s++) {                           // A: 2048 16B chunks
        int p = s * 512 + tid;
        int r = p >> 3, kc = (p & 7) ^ (r & 7);
        gload_lds16(Ag + (size_t)r * D + k0 + kc * 16, Asm + p * 16);
    }
    #pragma unroll
    for (int s = 0; s < 4; s++) {                           // B: 2048 16B chunks
        int p = s * 512 + tid;
        int r = p >> 3, kc = (p & 7) ^ (r & 7);
        gload_lds16(Bg + (size_t)r * D + k0 + kc * 16, Bsm + p * 16);
    }
}

// Kernel 1: per-row fp32 sum-of-squares (exact) + fp8(e4m3) cast + init.
__global__ void prep_kernel(const float* __restrict__ x,
                            unsigned char* __restrict__ x8,
                            float* __restrict__ sq,
                            unsigned int* __restrict__ apU,
                            unsigned int* __restrict__ anU,
                            int* __restrict__ cnt) {
    if (blockIdx.x == 0 && threadIdx.x == 0) cnt[0] = 0;
    int w = threadIdx.x >> 6, lane = threadIdx.x & 63;
    int row = blockIdx.x * 4 + w;
    const float4* p = (const float4*)(x + (size_t)row * D) + lane * 2;
    float4 v0 = p[0], v1 = p[1];
    float s = v0.x * v0.x + v0.y * v0.y + v0.z * v0.z + v0.w * v0.w
            + v1.x * v1.x + v1.y * v1.y + v1.z * v1.z + v1.w * v1.w;
    int w0 = __builtin_amdgcn_cvt_pk_fp8_f32(v0.x, v0.y, 0, false);
    w0     = __builtin_amdgcn_cvt_pk_fp8_f32(v0.z, v0.w, w0, true);
    int w1 = __builtin_amdgcn_cvt_pk_fp8_f32(v1.x, v1.y, 0, false);
    w1     = __builtin_amdgcn_cvt_pk_fp8_f32(v1.z, v1.w, w1, true);
    ((int2*)(x8 + (size_t)row * D))[lane] = make_int2(w0, w1);
    #pragma unroll
    for (int o = 32; o > 0; o >>= 1) s += __shfl_xor(s, o);
    if (lane == 0) {
        sq[row] = s;
        apU[row] = 0u;                 // max-d^2 accumulator (d^2 clamped >= 0)
        anU[row] = 0x7f800000u;        // min-d^2 accumulator (+inf)
    }
}

// Kernel 2: 256x256 bricks over the upper triangle (32 bands). Blocks
// 0..495 = off-diagonal (ri<cj), 496..527 = diagonal. Bijective XCD swizzle
// (528 = 8x66): consecutive swizzled ids share cj bands within an XCD -> L2
// locality for the B panel.
//
// Rationale: effective staging rate measured ~10-12 B/cy/CU across r1/r2/r4
// structures -> time ~ staged bytes. 256^2 bricks halve bytes/pair vs 128^2
// (135 MB total). K-loop: single-buffer 64 KB tiles, plain __syncthreads,
// frags to regs, stage ISSUED right after the mid-iter barrier so the next
// top-of-loop drain finds loads ~16 MFMAs old. 8 waves, grid 4(wm) x 2(wn):
// per-wave 64 rows x 128 cols, acc[4][8] = 128 AGPR.
//
// __launch_bounds__(512, 2): 2 waves/EU -> 256-VGPR budget. ROUND-5 BUG:
// (512,4) capped the allocator at 128 VGPR < the ~250 this kernel needs ->
// accumulator spilled to scratch (WRITE_SIZE 472 MB, 5x slowdown). 1 block/CU.
// Gram-matrix property: A and B fragments use the SAME loader, so any
// consistent K-permutation cancels. Diagonal bricks compute both halves
// redundantly (correct; 32/528 bricks).
__global__ __launch_bounds__(512, 2)
void gemm_kernel(const unsigned char* __restrict__ xb,
                 const float* __restrict__ sq,
                 const int* __restrict__ tgt,
                 unsigned int* __restrict__ apU,
                 unsigned int* __restrict__ anU) {
    __shared__ __align__(16) char smem_raw[65536];          // A 32K + B 32K
    __shared__ float sqI[256], sqJ[256];
    __shared__ int tI[256], tJ[256];

    unsigned char* Asm = (unsigned char*)smem_raw;
    unsigned char* Bsm = Asm + 32768;
    // epilogue scratch (aliases tiles; safe after last drain barrier)
    float* rowPap = (float*)smem_raw;                       // [256]
    float* rowPan = rowPap + 256;                           // [256]
    float* colPap = rowPan + 256;                           // [256][5]
    float* colPan = colPap + 256 * 5;                       // [256][5]

    // XCD-chunked bijective swizzle: 528 = 8 XCDs x 66 blocks.
    const int id = (blockIdx.x & 7) * 66 + (blockIdx.x >> 3);
    int ri, cj;
    if (id < NOFF) {
        cj = (int)((1.0f + sqrtf(1.0f + 8.0f * (float)id)) * 0.5f);
        while (cj * (cj - 1) / 2 > id) cj--;
        while ((cj + 1) * cj / 2 <= id) cj++;
        ri = id - cj * (cj - 1) / 2;                        // 0..cj-1
    } else {
        ri = cj = id - NOFF;                                // diagonal
    }
    const int rowBase = ri * 256, colBase = cj * 256;

    const int tid = threadIdx.x;
    const int w = tid >> 6, lane = tid & 63, q = lane >> 4, c = lane & 15;
    const int wm = w & 3, wn = w >> 2;                      // 64-row x 128-col/wave

    if (tid < 256) {
        sqI[tid] = sq[rowBase + tid]; tI[tid] = tgt[rowBase + tid];
        sqJ[tid] = sq[colBase + tid]; tJ[tid] = tgt[colBase + tid];
    }

    const unsigned char* Ag = xb + (size_t)rowBase * D;
    const unsigned char* Bg = xb + (size_t)colBase * D;

    f32x4 acc[4][8] = {};

    stage_tile(Ag, Asm, Bg, Bsm, tid, 0);                   // tile 0

    #pragma unroll
    for (int kk = 0; kk < 4; kk++) {                        // 4 K-iterations
        __syncthreads();                                    // tile kk ready (vmcnt drain)
        int8v af[4], b0[4];
        #pragma unroll
        for (int t = 0; t < 4; t++)
            af[t] = load_frag8(Asm, wm * 64 + t * 16 + c, q);
        #pragma unroll
        for (int t = 0; t < 4; t++)
            b0[t] = load_frag8(Bsm, wn * 128 + t * 16 + c, q);
        // first 16 MFMAs overlap b1's ds_reads
        #pragma unroll
        for (int tm = 0; tm < 4; tm++)
            #pragma unroll
            for (int t = 0; t < 4; t++)
                acc[tm][t] = __builtin_amdgcn_mfma_scale_f32_16x16x128_f8f6f4(
                    af[tm], b0[t], acc[tm][t],
                    0, 0,                                    // FMT A,B = fp8 e4m3
                    0, 0x7F7F7F7Fu, 0, 0x7F7F7F7Fu);         // scales = 1.0
        int8v b1[4];
        #pragma unroll
        for (int t = 0; t < 4; t++)
            b1[t] = load_frag8(Bsm, wn * 128 + (4 + t) * 16 + c, q);
        __syncthreads();                                    // all tile reads drained
        if (kk < 3)                                         // stage EARLY: next drain
            stage_tile(Ag, Asm, Bg, Bsm, tid, (kk + 1) * 128);  // finds loads old
        #pragma unroll
        for (int tm = 0; tm < 4; tm++)                      // 16 MFMAs cover the stage
            #pragma unroll
            for (int t = 0; t < 4; t++)
                acc[tm][4 + t] = __builtin_amdgcn_mfma_scale_f32_16x16x128_f8f6f4(
                    af[tm], b1[t], acc[tm][4 + t],
                    0, 0, 0, 0x7F7F7F7Fu, 0, 0x7F7F7F7Fu);
    }
    // After the last drain barrier no wave reads tiles again -> scratch aliasing
    // below is safe (epilogue readers wait on the epilogue barrier).

    // Epilogue. C/D layout is shape-determined: col=lane&15, row=q*4+reg.
    // d^2-space keys: rk = sq[j]-2p (row side), ck = sq[i]-2p (col side).
    // Row reduce: per-lane over tn, then shfl over c (16-lane group), then
    // cross-wave wn0/wn1 combine via LDS. Col reduce: per-lane over tm/r,
    // shfl over q, then cross-wave wm combine via LDS.
    float sjc[8]; int tjx[8];
    #pragma unroll
    for (int tn = 0; tn < 8; tn++) {
        int col_l = wn * 128 + tn * 16 + c;
        sjc[tn] = sqJ[col_l]; tjx[tn] = tJ[col_l];
    }
    float apc[8], anc[8];
    #pragma unroll
    for (int tn = 0; tn < 8; tn++) { apc[tn] = -1e30f; anc[tn] = 1e30f; }
    float rpk[4][4], rnk[4][4];                             // row partials (kept)
    #pragma unroll
    for (int tm = 0; tm < 4; tm++) {
        #pragma unroll
        for (int r = 0; r < 4; r++) {
            int row_l = wm * 64 + tm * 16 + q * 4 + r;
            float si = sqI[row_l]; int ti = tI[row_l];
            float rp = -1e30f, rn = 1e30f;
            #pragma unroll
            for (int tn = 0; tn < 8; tn++) {
                float p = acc[tm][tn][r];
                bool same = (ti == tjx[tn]);
                float rk = fmaf(-2.0f, p, sjc[tn]);         // row-side key
                float ck = fmaf(-2.0f, p, si);              // col-side key
                rp = fmaxf(rp, same ? rk : -1e30f);
                rn = fminf(rn, same ? 1e30f : rk);
                apc[tn] = fmaxf(apc[tn], same ? ck : -1e30f);
                anc[tn] = fminf(anc[tn], same ? 1e30f : ck);
            }
            #pragma unroll
            for (int o = 1; o < 16; o <<= 1) {              // reduce over c
                rp = fmaxf(rp, __shfl_xor(rp, o));
                rn = fminf(rn, __shfl_xor(rn, o));
            }
            rpk[tm][r] = rp; rnk[tm][r] = rn;
        }
    }
    // wn==1 publishes row partials
    if (wn == 1 && c == 0) {
        #pragma unroll
        for (int tm = 0; tm < 4; tm++)
            #pragma unroll
            for (int r = 0; r < 4; r++) {
                int row_l = wm * 64 + tm * 16 + q * 4 + r;
                rowPap[row_l] = rpk[tm][r];
                rowPan[row_l] = rnk[tm][r];
            }
    }
    // col partials: reduce over q (lanes differing in bits 4-5)
    #pragma unroll
    for (int tn = 0; tn < 8; tn++) {
        apc[tn] = fmaxf(apc[tn], __shfl_xor(apc[tn], 16));
        apc[tn] = fmaxf(apc[tn], __shfl_xor(apc[tn], 32));
        anc[tn] = fminf(anc[tn], __shfl_xor(anc[tn], 16));
        anc[tn] = fminf(anc[tn], __shfl_xor(anc[tn], 32));
    }
    if (q == 0) {                                           // lanes 0..15 publish
        #pragma unroll
        for (int tn = 0; tn < 8; tn++) {
            int col_l = wn * 128 + tn * 16 + c;
            colPap[col_l * 5 + wm] = apc[tn];
            colPan[col_l * 5 + wm] = anc[tn];
        }
    }
    __syncthreads();
    if (wn == 0 && c == 0) {                                // row finalize + atomic
        #pragma unroll
        for (int tm = 0; tm < 4; tm++)
            #pragma unroll
            for (int r = 0; r < 4; r++) {
                int row_l = wm * 64 + tm * 16 + q * 4 + r;
                float ap = fmaxf(rpk[tm][r], rowPap[row_l]);
                float an = fminf(rnk[tm][r], rowPan[row_l]);
                // restore true d^2, clamp >=0: uint-bit cmp == float cmp
                float apd = fmaxf(sqI[row_l] + ap, 0.0f);
                float and_ = fmaxf(sqI[row_l] + an, 0.0f);
                atomicMax(&apU[rowBase + row_l], __float_as_uint(apd));
                atomicMin(&anU[rowBase + row_l], __float_as_uint(and_));
            }
    }
    if (tid < 256) {                                        // col finalize + atomic
        float ap = -1e30f, an = 1e30f;
        #pragma unroll
        for (int u = 0; u < 4; u++) {
            ap = fmaxf(ap, colPap[tid * 5 + u]);
            an = fminf(an, colPan[tid * 5 + u]);
        }
        float apd = fmaxf(sqJ[tid] + ap, 0.0f);
        float and_ = fmaxf(sqJ[tid] + an, 0.0f);
        atomicMax(&apU[colBase + tid], __float_as_uint(apd));  // fire-and-forget
        atomicMin(&anU[colBase + tid], __float_as_uint(and_));
    }
}

// Kernel 3: per-row ap/an final in apU/anU -> sqrt + relu + mean; last block
// (atomic counter) folds the 32 block sums into out[0].
__global__ void reduce_kernel(const unsigned int* __restrict__ apU,
                              const unsigned int* __restrict__ anU,
                              float* __restrict__ bsum, int* __restrict__ cnt,
                              float* __restrict__ out) {
    int tid = threadIdx.x;
    int row = blockIdx.x * 256 + tid;
    float ap = __uint_as_float(apU[row]);
    float an = __uint_as_float(anU[row]);
    float dap = sqrtf(fmaxf(ap, 1e-12f));
    float dan = sqrtf(fmaxf(an, 1e-12f));
    float v = fmaxf(dap - dan + MARGIN, 0.0f);
    #pragma unroll
    for (int o = 32; o > 0; o >>= 1) v += __shfl_xor(v, o);
    __shared__ float ss[4];
    __shared__ int amLast;
    if ((tid & 63) == 0) ss[tid >> 6] = v;
    __syncthreads();
    if (tid == 0) {
        bsum[blockIdx.x] = ss[0] + ss[1] + ss[2] + ss[3];
        __threadfence();
        amLast = (atomicAdd(cnt, 1) == N / 256 - 1);
    }
    __syncthreads();
    if (amLast && tid < 64) {
        __threadfence();
        float t = (tid < N / 256) ? bsum[tid] : 0.0f;
        #pragma unroll
        for (int o = 32; o > 0; o >>= 1) t += __shfl_xor(t, o);
        if (tid == 0) out[0] = t * (1.0f / (float)N);
    }
}

extern "C" void kernel_launch(void* const* d_in, const int* in_sizes, int n_in,
                              void* d_out, int out_size, void* d_ws, size_t ws_size,
                              hipStream_t stream) {
    const float* x  = (const float*)d_in[0];
    const int* tgt  = (const int*)d_in[1];
    float* out      = (float*)d_out;

    char* ws = (char*)d_ws;
    unsigned char* x8 = (unsigned char*)ws;                         // 4 MB fp8 X
    float* sq   = (float*)(ws + (size_t)N * D);                     // 32 KB
    unsigned int* apU = (unsigned int*)(sq + N);                    // 32 KB
    unsigned int* anU = apU + N;                                    // 32 KB
    float* bsum = (float*)(anU + N);                                // 128 B
    int* cnt = (int*)(bsum + 32);

    prep_kernel<<<N / 4, 256, 0, stream>>>(x, x8, sq, apU, anU, cnt);
    gemm_kernel<<<NBRICKS, 512, 0, stream>>>(x8, sq, tgt, apU, anU);
    reduce_kernel<<<N / 256, 256, 0, stream>>>(apU, anU, bsum, cnt, out);
}

// Round 7
// 112.108 us; speedup vs baseline: 2.5271x; 1.1012x over previous
//
#include <hip/hip_runtime.h>

#define N 8192
#define D 512
#define NOFFD 2016                  // off-diagonal 128x128 bricks: 64*63/2
#define NDIAG 64                    // diagonal 128x128 bricks
#define NBRICKS (NOFFD + NDIAG)     // 2080 = 8 * 260 (clean XCD chunking)
#define MARGIN 0.3f

typedef __attribute__((ext_vector_type(4))) int int4v;
typedef __attribute__((ext_vector_type(8))) int int8v;      // 32 fp8 = 8 VGPRs
typedef __attribute__((ext_vector_type(4))) float f32x4;    // MFMA accumulator

// async global->LDS, 16B per lane; LDS dest = wave-uniform base + lane*16.
__device__ __forceinline__ void gload_lds16(const void* g, void* l) {
    __builtin_amdgcn_global_load_lds(
        (const __attribute__((address_space(1))) void*)g,
        (__attribute__((address_space(3))) void*)l,
        16, 0, 0);
}

// Load one 16x16x128 f8f6f4 operand fragment (32 fp8 = 32 B) for (row, quad)
// from a 128 B/row LDS tile with 16B-chunk XOR swizzle (phys = logi ^ (row&7)).
__device__ __forceinline__ int8v load_frag8(const unsigned char* base, int row, int q) {
    const int v = (2 * q) ^ (row & 7);
    int4v lo = *(const int4v*)(base + row * 128 + v * 16);
    int4v hi = *(const int4v*)(base + row * 128 + (v ^ 1) * 16);
    return __builtin_shufflevector(lo, hi, 0, 1, 2, 3, 4, 5, 6, 7);
}

// Stage one BK=128 K-tile (A 128x128B + B 128x128B fp8) with XOR source-swizzle.
// 256 threads -> 8 gload_lds per thread per tile (4 A + 4 B).
__device__ __forceinline__ void stage_tile(const unsigned char* Ag, unsigned char* Asm,
                                           const unsigned char* Bg, unsigned char* Bsm,
                                           int tid, int k0) {
    #pragma unroll
    for (int s = 0; s < 4; s++) {                           // A: 1024 16B chunks
        int p = s * 256 + tid;
        int r = p >> 3, kc = (p & 7) ^ (r & 7);
        gload_lds16(Ag + (size_t)r * D + k0 + kc * 16, Asm + p * 16);
    }
    #pragma unroll
    for (int s = 0; s < 4; s++) {                           // B: 1024 16B chunks
        int p = s * 256 + tid;
        int r = p >> 3, kc = (p & 7) ^ (r & 7);
        gload_lds16(Bg + (size_t)r * D + k0 + kc * 16, Bsm + p * 16);
    }
}

// Kernel 1: per-row fp32 sum-of-squares (exact) + fp8(e4m3) cast + init.
__global__ void prep_kernel(const float* __restrict__ x,
                            unsigned char* __restrict__ x8,
                            float* __restrict__ sq,
                            unsigned int* __restrict__ apU,
                            unsigned int* __restrict__ anU,
                            int* __restrict__ cnt) {
    if (blockIdx.x == 0 && threadIdx.x == 0) cnt[0] = 0;
    int w = threadIdx.x >> 6, lane = threadIdx.x & 63;
    int row = blockIdx.x * 4 + w;
    const float4* p = (const float4*)(x + (size_t)row * D) + lane * 2;
    float4 v0 = p[0], v1 = p[1];
    float s = v0.x * v0.x + v0.y * v0.y + v0.z * v0.z + v0.w * v0.w
            + v1.x * v1.x + v1.y * v1.y + v1.z * v1.z + v1.w * v1.w;
    int w0 = __builtin_amdgcn_cvt_pk_fp8_f32(v0.x, v0.y, 0, false);
    w0     = __builtin_amdgcn_cvt_pk_fp8_f32(v0.z, v0.w, w0, true);
    int w1 = __builtin_amdgcn_cvt_pk_fp8_f32(v1.x, v1.y, 0, false);
    w1     = __builtin_amdgcn_cvt_pk_fp8_f32(v1.z, v1.w, w1, true);
    ((int2*)(x8 + (size_t)row * D))[lane] = make_int2(w0, w1);
    #pragma unroll
    for (int o = 32; o > 0; o >>= 1) s += __shfl_xor(s, o);
    if (lane == 0) {
        sq[row] = s;
        apU[row] = 0u;                 // max-d^2 accumulator (d^2 clamped >= 0)
        anU[row] = 0x7f800000u;        // min-d^2 accumulator (+inf)
    }
}

// Kernel 2: 128x128 bricks over the upper triangle. Blocks 0..2015 =
// off-diagonal (ri<cj), 2016..2079 = diagonal. Bijective XCD swizzle
// (2080 = 8 x 260).
//
// OCCUPANCY BET (this round's single variable): staging rate was pinned at
// ~6.5 TB/s in every 8-waves/CU structure (r2/r4), but m97's ladder kernel
// sustains ~14 TB/s at 12 waves/CU. So: 3 lean blocks/CU. Single 32 KB tile
// buffer (no dbuf), 2 KB shfl-epilogue scratch (not 34 KB arrays), 37 KB LDS
// total, and __launch_bounds__(256,3) -> 170-reg budget (64 acc AGPR + ~100
// arch fits; r5 lesson: the 2nd arg is waves/EU and caps the allocator).
// K-loop is r2's proven 2-barrier shape: sync (tile ready) -> frag ds_reads
// -> sync (reads done) -> stage next EARLY -> MFMAs cover the new loads.
// Gram-matrix property: A and B fragments use the SAME loader, so any
// consistent K-permutation cancels. Diagonal bricks computed fully (64/2080).
__global__ __launch_bounds__(256, 3)
void gemm_kernel(const unsigned char* __restrict__ xb,
                 const float* __restrict__ sq,
                 const int* __restrict__ tgt,
                 unsigned int* __restrict__ apU,
                 unsigned int* __restrict__ anU) {
    __shared__ __align__(16) unsigned char Asm[16384];      // A tile (swizzled)
    __shared__ __align__(16) unsigned char Bsm[16384];      // B tile (swizzled)
    __shared__ float sqI[128], sqJ[128];
    __shared__ int tI[128], tJ[128];
    __shared__ float rowPap[128], rowPan[128];              // cross-wave scratch
    __shared__ float colPap[128], colPan[128];

    // XCD-chunked bijective swizzle: 2080 = 8 XCDs x 260 blocks.
    const int id = (blockIdx.x & 7) * 260 + (blockIdx.x >> 3);
    int ri, cj;
    if (id < NOFFD) {
        cj = (int)((1.0f + sqrtf(1.0f + 8.0f * (float)id)) * 0.5f);
        while (cj * (cj - 1) / 2 > id) cj--;
        while ((cj + 1) * cj / 2 <= id) cj++;
        ri = id - cj * (cj - 1) / 2;                        // 0..cj-1
    } else {
        ri = cj = id - NOFFD;                               // diagonal
    }
    const int rowBase = ri * 128, colBase = cj * 128;

    const int tid = threadIdx.x;
    const int w = tid >> 6, lane = tid & 63, q = lane >> 4, c = lane & 15;
    const int wm = w & 1, wn = w >> 1;                      // 64x64 sub-tile/wave

    if (tid < 128) {
        sqI[tid] = sq[rowBase + tid]; tI[tid] = tgt[rowBase + tid];
        sqJ[tid] = sq[colBase + tid]; tJ[tid] = tgt[colBase + tid];
    }

    const unsigned char* Ag = xb + (size_t)rowBase * D;
    const unsigned char* Bg = xb + (size_t)colBase * D;

    f32x4 acc[4][4] = {};

    stage_tile(Ag, Asm, Bg, Bsm, tid, 0);                   // tile 0

    #pragma unroll
    for (int kk = 0; kk < 4; kk++) {                        // 4 K-iterations
        __syncthreads();                                    // tile kk ready (drain)
        int8v af[4], bf[4];
        #pragma unroll
        for (int t = 0; t < 4; t++)
            af[t] = load_frag8(Asm, wm * 64 + t * 16 + c, q);
        #pragma unroll
        for (int t = 0; t < 4; t++)
            bf[t] = load_frag8(Bsm, wn * 64 + t * 16 + c, q);
        __syncthreads();                                    // all tile reads done
        if (kk < 3)                                         // stage EARLY: 16 MFMAs
            stage_tile(Ag, Asm, Bg, Bsm, tid, (kk + 1) * 128);  // cover the loads
        #pragma unroll
        for (int tm = 0; tm < 4; tm++)
            #pragma unroll
            for (int t = 0; t < 4; t++)
                acc[tm][t] = __builtin_amdgcn_mfma_scale_f32_16x16x128_f8f6f4(
                    af[tm], bf[t], acc[tm][t],
                    0, 0,                                    // FMT A,B = fp8 e4m3
                    0, 0x7F7F7F7Fu, 0, 0x7F7F7F7Fu);         // scales = 1.0
    }

    // Epilogue. C/D layout is shape-determined: col=lane&15, row=q*4+reg.
    // d^2-space keys: rk = sq[j]-2p (row side), ck = sq[i]-2p (col side).
    // Row reduce: in-lane over tn -> shfl over c -> cross-wave wn via LDS.
    // Col reduce: in-lane over tm/r -> shfl over q -> cross-wave wm via LDS.
    // Scratch is SEPARATE from tiles (no alias hazard with in-flight stages).
    float sjc[4]; int tjx[4];
    #pragma unroll
    for (int tn = 0; tn < 4; tn++) {
        int col_l = wn * 64 + tn * 16 + c;
        sjc[tn] = sqJ[col_l]; tjx[tn] = tJ[col_l];
    }
    float apc[4], anc[4];
    #pragma unroll
    for (int tn = 0; tn < 4; tn++) { apc[tn] = -1e30f; anc[tn] = 1e30f; }
    float rpk[4][4], rnk[4][4];
    #pragma unroll
    for (int tm = 0; tm < 4; tm++) {
        #pragma unroll
        for (int r = 0; r < 4; r++) {
            int row_l = wm * 64 + tm * 16 + q * 4 + r;
            float si = sqI[row_l]; int ti = tI[row_l];
            float rp = -1e30f, rn = 1e30f;
            #pragma unroll
            for (int tn = 0; tn < 4; tn++) {
                float p = acc[tm][tn][r];
                bool same = (ti == tjx[tn]);
                float rk = fmaf(-2.0f, p, sjc[tn]);         // row-side key
                float ck = fmaf(-2.0f, p, si);              // col-side key
                rp = fmaxf(rp, same ? rk : -1e30f);
                rn = fminf(rn, same ? 1e30f : rk);
                apc[tn] = fmaxf(apc[tn], same ? ck : -1e30f);
                anc[tn] = fminf(anc[tn], same ? 1e30f : ck);
            }
            #pragma unroll
            for (int o = 1; o < 16; o <<= 1) {              // reduce over c
                rp = fmaxf(rp, __shfl_xor(rp, o));
                rn = fminf(rn, __shfl_xor(rn, o));
            }
            rpk[tm][r] = rp; rnk[tm][r] = rn;
        }
    }
    if (wn == 1 && c == 0) {                                // publish row partials
        #pragma unroll
        for (int tm = 0; tm < 4; tm++)
            #pragma unroll
            for (int r = 0; r < 4; r++) {
                int row_l = wm * 64 + tm * 16 + q * 4 + r;
                rowPap[row_l] = rpk[tm][r];
                rowPan[row_l] = rnk[tm][r];
            }
    }
    #pragma unroll
    for (int tn = 0; tn < 4; tn++) {                        // reduce over q
        apc[tn] = fmaxf(apc[tn], __shfl_xor(apc[tn], 16));
        apc[tn] = fmaxf(apc[tn], __shfl_xor(apc[tn], 32));
        anc[tn] = fminf(anc[tn], __shfl_xor(anc[tn], 16));
        anc[tn] = fminf(anc[tn], __shfl_xor(anc[tn], 32));
    }
    if (wm == 1 && q == 0) {                                // publish col partials
        #pragma unroll
        for (int tn = 0; tn < 4; tn++) {
            int col_l = wn * 64 + tn * 16 + c;
            colPap[col_l] = apc[tn];
            colPan[col_l] = anc[tn];
        }
    }
    __syncthreads();
    if (wn == 0 && c == 0) {                                // row finalize + atomic
        #pragma unroll
        for (int tm = 0; tm < 4; tm++)
            #pragma unroll
            for (int r = 0; r < 4; r++) {
                int row_l = wm * 64 + tm * 16 + q * 4 + r;
                float ap = fmaxf(rpk[tm][r], rowPap[row_l]);
                float an = fminf(rnk[tm][r], rowPan[row_l]);
                // restore true d^2, clamp >=0: uint-bit cmp == float cmp
                float apd = fmaxf(sqI[row_l] + ap, 0.0f);
                float and_ = fmaxf(sqI[row_l] + an, 0.0f);
                atomicMax(&apU[rowBase + row_l], __float_as_uint(apd));
                atomicMin(&anU[rowBase + row_l], __float_as_uint(and_));
            }
    }
    if (wm == 0 && q == 0) {                                // col finalize + atomic
        #pragma unroll
        for (int tn = 0; tn < 4; tn++) {
            int col_l = wn * 64 + tn * 16 + c;
            float ap = fmaxf(apc[tn], colPap[col_l]);
            float an = fminf(anc[tn], colPan[col_l]);
            float apd = fmaxf(sqJ[col_l] + ap, 0.0f);
            float and_ = fmaxf(sqJ[col_l] + an, 0.0f);
            atomicMax(&apU[colBase + col_l], __float_as_uint(apd));
            atomicMin(&anU[colBase + col_l], __float_as_uint(and_));
        }
    }
}

// Kernel 3: per-row ap/an final in apU/anU -> sqrt + relu + mean; last block
// (atomic counter) folds the 32 block sums into out[0].
__global__ void reduce_kernel(const unsigned int* __restrict__ apU,
                              const unsigned int* __restrict__ anU,
                              float* __restrict__ bsum, int* __restrict__ cnt,
                              float* __restrict__ out) {
    int tid = threadIdx.x;
    int row = blockIdx.x * 256 + tid;
    float ap = __uint_as_float(apU[row]);
    float an = __uint_as_float(anU[row]);
    float dap = sqrtf(fmaxf(ap, 1e-12f));
    float dan = sqrtf(fmaxf(an, 1e-12f));
    float v = fmaxf(dap - dan + MARGIN, 0.0f);
    #pragma unroll
    for (int o = 32; o > 0; o >>= 1) v += __shfl_xor(v, o);
    __shared__ float ss[4];
    __shared__ int amLast;
    if ((tid & 63) == 0) ss[tid >> 6] = v;
    __syncthreads();
    if (tid == 0) {
        bsum[blockIdx.x] = ss[0] + ss[1] + ss[2] + ss[3];
        __threadfence();
        amLast = (atomicAdd(cnt, 1) == N / 256 - 1);
    }
    __syncthreads();
    if (amLast && tid < 64) {
        __threadfence();
        float t = (tid < N / 256) ? bsum[tid] : 0.0f;
        #pragma unroll
        for (int o = 32; o > 0; o >>= 1) t += __shfl_xor(t, o);
        if (tid == 0) out[0] = t * (1.0f / (float)N);
    }
}

extern "C" void kernel_launch(void* const* d_in, const int* in_sizes, int n_in,
                              void* d_out, int out_size, void* d_ws, size_t ws_size,
                              hipStream_t stream) {
    const float* x  = (const float*)d_in[0];
    const int* tgt  = (const int*)d_in[1];
    float* out      = (float*)d_out;

    char* ws = (char*)d_ws;
    unsigned char* x8 = (unsigned char*)ws;                         // 4 MB fp8 X
    float* sq   = (float*)(ws + (size_t)N * D);                     // 32 KB
    unsigned int* apU = (unsigned int*)(sq + N);                    // 32 KB
    unsigned int* anU = apU + N;                                    // 32 KB
    float* bsum = (float*)(anU + N);                                // 128 B
    int* cnt = (int*)(bsum + 32);

    prep_kernel<<<N / 4, 256, 0, stream>>>(x, x8, sq, apU, anU, cnt);
    gemm_kernel<<<NBRICKS, 256, 0, stream>>>(x8, sq, tgt, apU, anU);
    reduce_kernel<<<N / 256, 256, 0, stream>>>(apU, anU, bsum, cnt, out);
}

// Round 8
// 100.604 us; speedup vs baseline: 2.8161x; 1.1144x over previous
//
#include <hip/hip_runtime.h>

#define N 8192
#define D 512
#define NSB 32                      // 32 col superblocks (256 cols)
#define NFULL 1024                  // full 128x256 bricks: sum(2*bj2+1) = 32^2
#define NQ 64                       // 64 diagonal quarter-bricks (128x64)
#define NBRICKS (NFULL + NQ)        // 1088 = 8 * 136 (bijective XCD chunking)
#define MARGIN 0.3f

typedef __attribute__((ext_vector_type(4))) int int4v;
typedef __attribute__((ext_vector_type(8))) int int8v;      // 32 fp8 = 8 VGPRs
typedef __attribute__((ext_vector_type(4))) float f32x4;    // MFMA accumulator

// async global->LDS, 16B per lane; LDS dest = wave-uniform base + lane*16.
__device__ __forceinline__ void gload_lds16(const void* g, void* l) {
    __builtin_amdgcn_global_load_lds(
        (const __attribute__((address_space(1))) void*)g,
        (__attribute__((address_space(3))) void*)l,
        16, 0, 0);
}

// Load one 16x16x128 f8f6f4 operand fragment (32 fp8 = 32 B) for (row, quad)
// from a 128 B/row LDS tile with 16B-chunk XOR swizzle (phys = logi ^ (row&7)).
// Logical chunks 2q and 2q+1 live at v and v^1.
__device__ __forceinline__ int8v load_frag8(const unsigned char* base, int row, int q) {
    const int v = (2 * q) ^ (row & 7);
    int4v lo = *(const int4v*)(base + row * 128 + v * 16);
    int4v hi = *(const int4v*)(base + row * 128 + (v ^ 1) * 16);
    return __builtin_shufflevector(lo, hi, 0, 1, 2, 3, 4, 5, 6, 7);
}

// Stage the (A 128x128, B NC x128) fp8 K-tiles into LDS with XOR source-swizzle.
template <int TN>
__device__ __forceinline__ void stage_tiles(const unsigned char* Ag, const unsigned char* Bg,
                                            unsigned char* Asm, unsigned char* Bsm,
                                            int tid, int k0) {
    #pragma unroll
    for (int s = 0; s < 4; s++) {                           // A: 1024 16B chunks
        int p = s * 256 + tid;
        int r = p >> 3, kc = (p & 7) ^ (r & 7);
        gload_lds16(Ag + (size_t)r * D + k0 + kc * 16, Asm + p * 16);
    }
    #pragma unroll
    for (int s = 0; s < TN; s++) {                          // B: NC*8 chunks
        int p = s * 256 + tid;
        int r = p >> 3, kc = (p & 7) ^ (r & 7);
        gload_lds16(Bg + (size_t)r * D + k0 + kc * 16, Bsm + p * 16);
    }
}

// Kernel 1: per-row fp32 sum-of-squares (exact) + fp8(e4m3) cast + init.
__global__ void prep_kernel(const float* __restrict__ x,
                            unsigned char* __restrict__ x8,
                            float* __restrict__ sq,
                            unsigned int* __restrict__ apU,
                            unsigned int* __restrict__ anU,
                            int* __restrict__ cnt) {
    if (blockIdx.x == 0 && threadIdx.x == 0) cnt[0] = 0;
    int w = threadIdx.x >> 6, lane = threadIdx.x & 63;
    int row = blockIdx.x * 4 + w;
    const float4* p = (const float4*)(x + (size_t)row * D) + lane * 2;
    float4 v0 = p[0], v1 = p[1];
    float s = v0.x * v0.x + v0.y * v0.y + v0.z * v0.z + v0.w * v0.w
            + v1.x * v1.x + v1.y * v1.y + v1.z * v1.z + v1.w * v1.w;
    int w0 = __builtin_amdgcn_cvt_pk_fp8_f32(v0.x, v0.y, 0, false);
    w0     = __builtin_amdgcn_cvt_pk_fp8_f32(v0.z, v0.w, w0, true);
    int w1 = __builtin_amdgcn_cvt_pk_fp8_f32(v1.x, v1.y, 0, false);
    w1     = __builtin_amdgcn_cvt_pk_fp8_f32(v1.z, v1.w, w1, true);
    ((int2*)(x8 + (size_t)row * D))[lane] = make_int2(w0, w1);
    #pragma unroll
    for (int o = 32; o > 0; o >>= 1) s += __shfl_xor(s, o);
    if (lane == 0) {
        sq[row] = s;
        apU[row] = 0u;                 // max-d^2 accumulator (d^2 clamped >= 0)
        anU[row] = 0x7f800000u;        // min-d^2 accumulator (+inf)
    }
}

// Brick body, MX-fp8 (K=128) MFMA, scales = 1.0 (0x7F E8M0) -> HW identity.
// TN=8 -> 128x256 full brick; TN=2 -> 128x64 diagonal quarter. BK=128
// single-buffer staging, with the stage ISSUE moved before the second MFMA
// cluster: per K-iter, all tile reads complete -> barrier -> issue next
// tile's global_load_lds -> run MFMAs. The implicit vmcnt(0) drain at the
// next barrier then finds the loads ~16 MFMAs old instead of fresh (T14).
// This is the measured-best structure (r2: gemm 33.7 us, 6.2 TB/s staging;
// r3/r4/r6/r7 restructures all regressed -- staging rate is pinned ~6.5 TB/s
// whenever >=2 independent blocks/CU, so bytes/output is the only lever and
// 128x256 is the feasible-region optimum).
// Gram-matrix property: A and B fragments use the SAME loader, so any
// consistent K-permutation cancels.
template <int TN>
__device__ __forceinline__ void brick_body(
    int rowBase, int colBase,
    const unsigned char* __restrict__ xb, const float* __restrict__ sq,
    const int* __restrict__ tgt,
    unsigned int* __restrict__ apU, unsigned int* __restrict__ anU,
    char* smem_raw, float* sqI, float* sqJ, int* tI, int* tJ) {
    constexpr int NC = TN * 32;                             // brick cols
    unsigned char* Asm = (unsigned char*)smem_raw;          // [128][128] fp8 swizzled
    unsigned char* Bsm = Asm + 128 * 128;                   // [NC][128] fp8 swizzled
    float* redAp = (float*)smem_raw;                        // [128][34]
    float* redAn = redAp + 128 * 34;
    float* colAp = (float*)smem_raw;                        // [NC][10] (phase 2)
    float* colAn = colAp + NC * 10;

    const int tid = threadIdx.x;
    const int w = tid >> 6, lane = tid & 63, q = lane >> 4, c = lane & 15;
    const int wm = w & 1, wn = w >> 1;                      // 64-row x (TN*16)-col/wave

    if (tid < 128) { sqI[tid] = sq[rowBase + tid]; tI[tid] = tgt[rowBase + tid]; }
    if (tid < NC)  { sqJ[tid] = sq[colBase + tid]; tJ[tid] = tgt[colBase + tid]; }

    const unsigned char* Ag = xb + (size_t)rowBase * D;
    const unsigned char* Bg = xb + (size_t)colBase * D;

    f32x4 acc[4][TN] = {};

    stage_tiles<TN>(Ag, Bg, Asm, Bsm, tid, 0);              // prologue stage

    #pragma unroll
    for (int kk = 0; kk < 4; kk++) {                        // 4 K-iterations
        __syncthreads();                                    // vmcnt drained -> tile ready
        int8v af[4];
        #pragma unroll
        for (int t = 0; t < 4; t++)
            af[t] = load_frag8(Asm, wm * 64 + t * 16 + c, q);
        constexpr int TB = (TN < 4) ? TN : 4;
        int8v b0[TB];
        #pragma unroll
        for (int t = 0; t < TB; t++)
            b0[t] = load_frag8(Bsm, wn * (TN * 16) + t * 16 + c, q);

        if constexpr (TN == 8) {
            // First 16 MFMAs overlap b1's ds_reads (separate pipes).
            #pragma unroll
            for (int tm = 0; tm < 4; tm++)
                #pragma unroll
                for (int t = 0; t < 4; t++)
                    acc[tm][t] = __builtin_amdgcn_mfma_scale_f32_16x16x128_f8f6f4(
                        af[tm], b0[t], acc[tm][t],
                        0, 0, 0, 0x7F7F7F7Fu, 0, 0x7F7F7F7Fu);
            int8v b1[4];
            #pragma unroll
            for (int t = 0; t < 4; t++)
                b1[t] = load_frag8(Bsm, wn * 128 + (4 + t) * 16 + c, q);
            __syncthreads();                                // all tile reads done
            if (kk < 3)                                     // issue next stage EARLY
                stage_tiles<8>(Ag, Bg, Asm, Bsm, tid, (kk + 1) * 128);
            #pragma unroll
            for (int tm = 0; tm < 4; tm++)                  // 16 MFMAs cover the loads
                #pragma unroll
                for (int t = 0; t < 4; t++)
                    acc[tm][4 + t] = __builtin_amdgcn_mfma_scale_f32_16x16x128_f8f6f4(
                        af[tm], b1[t], acc[tm][4 + t],
                        0, 0, 0, 0x7F7F7F7Fu, 0, 0x7F7F7F7Fu);
        } else {
            __syncthreads();                                // all tile reads done
            if (kk < 3)
                stage_tiles<TN>(Ag, Bg, Asm, Bsm, tid, (kk + 1) * 128);
            #pragma unroll
            for (int tm = 0; tm < 4; tm++)                  // 8 MFMAs cover the loads
                #pragma unroll
                for (int t = 0; t < TB; t++)
                    acc[tm][t] = __builtin_amdgcn_mfma_scale_f32_16x16x128_f8f6f4(
                        af[tm], b0[t], acc[tm][t],
                        0, 0, 0, 0x7F7F7F7Fu, 0, 0x7F7F7F7Fu);
        }
    }

    // Epilogue (unchanged; C/D layout is shape-determined: col=lane&15,
    // row=q*4+reg). d^2-space selection keys. Tiles are dead: after the last
    // iteration's second barrier no wave touches Asm/Bsm again.
    float sjc[TN]; int tjx[TN];
    #pragma unroll
    for (int tn = 0; tn < TN; tn++) {
        int col_l = wn * (TN * 16) + tn * 16 + c;
        sjc[tn] = sqJ[col_l]; tjx[tn] = tJ[col_l];
    }
    float apc[TN], anc[TN];
    #pragma unroll
    for (int tn = 0; tn < TN; tn++) { apc[tn] = -1e30f; anc[tn] = 1e30f; }
    #pragma unroll
    for (int tm = 0; tm < 4; tm++) {
        #pragma unroll
        for (int r = 0; r < 4; r++) {
            int row_l = wm * 64 + tm * 16 + q * 4 + r;
            float si = sqI[row_l]; int ti = tI[row_l];
            float rp = -1e30f, rn = 1e30f;
            #pragma unroll
            for (int tn = 0; tn < TN; tn++) {
                float p = acc[tm][tn][r];
                bool same = (ti == tjx[tn]);
                float rk = fmaf(-2.0f, p, sjc[tn]);         // row-side key
                float ck = fmaf(-2.0f, p, si);              // col-side key
                rp = fmaxf(rp, same ? rk : -1e30f);
                rn = fminf(rn, same ? 1e30f : rk);
                apc[tn] = fmaxf(apc[tn], same ? ck : -1e30f);
                anc[tn] = fminf(anc[tn], same ? 1e30f : ck);
            }
            redAp[row_l * 34 + wn * 16 + c] = rp;           // tiles dead (post-barrier)
            redAn[row_l * 34 + wn * 16 + c] = rn;
        }
    }
    __syncthreads();
    if (tid < 128) {                                        // row finalize
        float ap = -1e30f, an = 1e30f;
        #pragma unroll 8
        for (int u = 0; u < 32; u++) {
            ap = fmaxf(ap, redAp[tid * 34 + u]);
            an = fminf(an, redAn[tid * 34 + u]);
        }
        // restore true d^2, clamp >=0 so uint-bit compare == float compare
        float apd = fmaxf(sqI[tid] + ap, 0.0f);
        float and_ = fmaxf(sqI[tid] + an, 0.0f);
        atomicMax(&apU[rowBase + tid], __float_as_uint(apd));
        atomicMin(&anU[rowBase + tid], __float_as_uint(and_));
    }
    __syncthreads();                                        // row phase done
    #pragma unroll
    for (int tn = 0; tn < TN; tn++) {
        int col_l = wn * (TN * 16) + tn * 16 + c;
        colAp[col_l * 10 + wm * 4 + q] = apc[tn];
        colAn[col_l * 10 + wm * 4 + q] = anc[tn];
    }
    __syncthreads();
    if (tid < NC) {
        float ap = -1e30f, an = 1e30f;
        #pragma unroll
        for (int u = 0; u < 8; u++) {
            ap = fmaxf(ap, colAp[tid * 10 + u]);
            an = fminf(an, colAn[tid * 10 + u]);
        }
        float apd = fmaxf(sqJ[tid] + ap, 0.0f);
        float and_ = fmaxf(sqJ[tid] + an, 0.0f);
        atomicMax(&apU[colBase + tid], __float_as_uint(apd));  // fire-and-forget
        atomicMin(&anU[colBase + tid], __float_as_uint(and_));
    }
}

// Kernel 2: swizzled ids 0..1023 = full bricks (bj2 = isqrt(id),
// bi = id - bj2^2); ids 1024..1087 = diagonal quarter-bricks (128x64).
// XCD-chunked bijective swizzle (1088 = 8 x 136): each XCD gets a contiguous
// id run; consecutive ids share the same 256-col B superblock for runs of
// 2*bj2+1 bricks -> B panel becomes L2-resident per XCD (T1 regime: real
// inter-block panel sharing). This is the ONLY change vs the round-2 kernel
// (measured best: gemm 33.7 us, total 98.9 us).
__global__ __launch_bounds__(256, 2)
void gemm_kernel(const unsigned char* __restrict__ xb,
                 const float* __restrict__ sq,
                 const int* __restrict__ tgt,
                 unsigned int* __restrict__ apU,
                 unsigned int* __restrict__ anU) {
    __shared__ __align__(16) char smem_raw[49152];
    __shared__ float sqI[128], sqJ[256];
    __shared__ int tI[128], tJ[256];

    const int id = (blockIdx.x & 7) * 136 + (blockIdx.x >> 3);  // bijective
    if (id < NFULL) {
        int bj2 = (int)sqrtf((float)id + 0.5f);
        while (bj2 * bj2 > id) bj2--;
        while ((bj2 + 1) * (bj2 + 1) <= id) bj2++;
        const int bi = id - bj2 * bj2;                      // 0..2*bj2
        brick_body<8>(bi * 128, bj2 * 256, xb, sq, tgt, apU, anU,
                      smem_raw, sqI, sqJ, tI, tJ);
    } else {
        const int h = id - NFULL;                           // 0..63
        const int j = h >> 1, side = h & 1;
        brick_body<2>((2 * j + 1) * 128, j * 256 + 128 + side * 64,
                      xb, sq, tgt, apU, anU, smem_raw, sqI, sqJ, tI, tJ);
    }
}

// Kernel 3: per-row ap/an final in apU/anU -> sqrt + relu + mean; last block
// (atomic counter) folds the 32 block sums into out[0].
__global__ void reduce_kernel(const unsigned int* __restrict__ apU,
                              const unsigned int* __restrict__ anU,
                              float* __restrict__ bsum, int* __restrict__ cnt,
                              float* __restrict__ out) {
    int tid = threadIdx.x;
    int row = blockIdx.x * 256 + tid;
    float ap = __uint_as_float(apU[row]);
    float an = __uint_as_float(anU[row]);
    float dap = sqrtf(fmaxf(ap, 1e-12f));
    float dan = sqrtf(fmaxf(an, 1e-12f));
    float v = fmaxf(dap - dan + MARGIN, 0.0f);
    #pragma unroll
    for (int o = 32; o > 0; o >>= 1) v += __shfl_xor(v, o);
    __shared__ float ss[4];
    __shared__ int amLast;
    if ((tid & 63) == 0) ss[tid >> 6] = v;
    __syncthreads();
    if (tid == 0) {
        bsum[blockIdx.x] = ss[0] + ss[1] + ss[2] + ss[3];
        __threadfence();
        amLast = (atomicAdd(cnt, 1) == N / 256 - 1);
    }
    __syncthreads();
    if (amLast && tid < 64) {
        __threadfence();
        float t = (tid < N / 256) ? bsum[tid] : 0.0f;
        #pragma unroll
        for (int o = 32; o > 0; o >>= 1) t += __shfl_xor(t, o);
        if (tid == 0) out[0] = t * (1.0f / (float)N);
    }
}

extern "C" void kernel_launch(void* const* d_in, const int* in_sizes, int n_in,
                              void* d_out, int out_size, void* d_ws, size_t ws_size,
                              hipStream_t stream) {
    const float* x  = (const float*)d_in[0];
    const int* tgt  = (const int*)d_in[1];
    float* out      = (float*)d_out;

    char* ws = (char*)d_ws;
    unsigned char* x8 = (unsigned char*)ws;                         // 4 MB fp8 X
    float* sq   = (float*)(ws + (size_t)N * D);                     // 32 KB
    unsigned int* apU = (unsigned int*)(sq + N);                    // 32 KB
    unsigned int* anU = apU + N;                                    // 32 KB
    float* bsum = (float*)(anU + N);                                // 128 B
    int* cnt = (int*)(bsum + 32);

    prep_kernel<<<N / 4, 256, 0, stream>>>(x, x8, sq, apU, anU, cnt);
    gemm_kernel<<<NBRICKS, 256, 0, stream>>>(x8, sq, tgt, apU, anU);
    reduce_kernel<<<N / 256, 256, 0, stream>>>(apU, anU, bsum, cnt, out);
}